// Round 8
// baseline (131.727 us; speedup 1.0000x reference)
//
#include <hip/hip_runtime.h>

// Fused MLPKAN, round 8: batch-partitioned waves, L1-resident weight stream.
// Block = 512 thr (8 waves), TB = 64 batches, grid = 256 (1 block/CU).
// All 8 waves sweep the SAME i together -> per-i weight row (3.3 KB) is
// loaded by wave 0 from L2 and L1-hit by the other 7 (round 5..7 streamed 4
// disjoint 53 KB slices through 32 KB L1: 0% hits, every load ~200cyc L2).
// Each wave owns its 8 batches end-to-end: NO cross-wave partials, no
// combine pass, no shfl reduction.
//   Layer0: lane = o (coalesced weight row), acc = 4 v2f (8 batches packed
//           in pairs), activations = 2x ds_read_b128 broadcast of xs[i][.].
//   Layer1: lane = bg*16+o1; each lane 2 batches (1 v2f) over all 64 i;
//           activation = ds_read_b64 ht[i][2bg+boff] (distinct banks per bg).
// Weights: 1-deep software-pipelined prefetch, #pragma unroll 1 (spill-safe).

typedef float v2f __attribute__((ext_vector_type(2)));

#define BATCH 16384
#define TB    64

__global__ __launch_bounds__(512, 2) void kan_fused(
    const float* __restrict__ x,
    const float* __restrict__ A1, const float* __restrict__ a1,
    const float* __restrict__ A2, const float* __restrict__ a2,
    const float* __restrict__ A3, const float* __restrict__ a3,
    const float* __restrict__ B1, const float* __restrict__ c1,
    const float* __restrict__ B2, const float* __restrict__ c2,
    const float* __restrict__ B3, const float* __restrict__ c3,
    float* __restrict__ out)
{
    __shared__ float xs[64][68];   // x transposed: xs[i][b]; pad 68 keeps 16B align
    __shared__ float ht[64][68];   // h transposed: ht[i][b]

    const int t    = threadIdx.x;
    const int lane = t & 63;
    const int wave = t >> 6;            // 0..7 = batch-octant
    const int boff = 8 * wave;          // this wave's 8 batches
    const int bB0  = blockIdx.x * TB;

    // ---- stage x transposed: 4096 floats, 512 thr x 2 float4 ----
#pragma unroll
    for (int k = t * 4; k < TB * 64; k += 512 * 4) {
        const float4 v = *(const float4*)(x + (long)bB0 * 64 + k);
        const int b = k >> 6, i = k & 63;
        xs[i][b] = v.x; xs[i + 1][b] = v.y; xs[i + 2][b] = v.z; xs[i + 3][b] = v.w;
    }
    __syncthreads();

    const v2f zz = {0.f, 0.f};

    // ================= layer 0: 64 -> 64, all waves sweep all i =================
    {
        const int o = lane;

        auto ldw = [&](int i, v2f& w1, v2f& d1, float4& w2, v2f& d2, v2f& w3, float& b3v) {
            const int n = (i << 6) + o;
            w1  = *(const v2f*)(A1 + 2 * n);
            d1  = *(const v2f*)(a1 + 2 * n);
            w2  = *(const float4*)(A2 + 4 * n);
            d2  = *(const v2f*)(a2 + 2 * n);
            w3  = *(const v2f*)(A3 + 2 * n);
            b3v = a3[n];
        };

        v2f acc[4];
#pragma unroll
        for (int j = 0; j < 4; ++j) acc[j] = zz;
        float bsum = 0.f;

        v2f w1, d1, d2, w3; float4 w2; float b3v;
        ldw(0, w1, d1, w2, d2, w3, b3v);

#pragma unroll 1
        for (int ii = 0; ii < 64; ++ii) {
            v2f nw1, nd1, nd2, nw3; float4 nw2; float nb3;
            ldw((ii + 1) & 63, nw1, nd1, nw2, nd2, nw3, nb3);   // in flight (L1-hot)

            const v2f W1X = {w1.x, w1.x}, W1Y = {w1.y, w1.y};
            const v2f D1X = {d1.x, d1.x}, D1Y = {d1.y, d1.y};
            const v2f W2X = {w2.x, w2.x}, W2Y = {w2.y, w2.y};
            const v2f W2Z = {w2.z, w2.z}, W2W = {w2.w, w2.w};
            const v2f D2X = {d2.x, d2.x}, D2Y = {d2.y, d2.y};
            const v2f W3X = {w3.x, w3.x}, W3Y = {w3.y, w3.y};

            const float4 xv0 = *(const float4*)&xs[ii][boff];       // broadcast b128
            const float4 xv1 = *(const float4*)&xs[ii][boff + 4];
            const float4 xq[2] = {xv0, xv1};
            const v2f* xp = (const v2f*)xq;

            bsum += b3v;
#pragma unroll
            for (int jp = 0; jp < 4; ++jp) {                        // 2 batches/iter
                v2f m0 = __builtin_elementwise_fma(xp[jp], W1X, D1X);
                v2f m1 = __builtin_elementwise_fma(xp[jp], W1Y, D1Y);
                m0 = __builtin_elementwise_max(m0, zz);
                m1 = __builtin_elementwise_max(m1, zz);
                v2f t0 = __builtin_elementwise_fma(W2Y, m1, D2X);
                t0 = __builtin_elementwise_fma(W2X, m0, t0);
                v2f t1 = __builtin_elementwise_fma(W2W, m1, D2Y);
                t1 = __builtin_elementwise_fma(W2Z, m0, t1);
                t0 = __builtin_elementwise_max(t0, zz);
                t1 = __builtin_elementwise_max(t1, zz);
                acc[jp] = __builtin_elementwise_fma(W3X, t0, acc[jp]);
                acc[jp] = __builtin_elementwise_fma(W3Y, t1, acc[jp]);
            }
            w1 = nw1; d1 = nd1; w2 = nw2; d2 = nd2; w3 = nw3; b3v = nb3;
        }
        // write this wave's 8 batches, transposed for layer 1
#pragma unroll
        for (int jp = 0; jp < 4; ++jp) {
            ht[o][boff + 2 * jp]     = acc[jp].x + bsum;
            ht[o][boff + 2 * jp + 1] = acc[jp].y + bsum;
        }
    }
    __syncthreads();

    // ================= layer 1: 64 -> 16 =================
    {
        const int o1 = lane & 15;
        const int bg = lane >> 4;            // 4 batch-pairs per wave
        const int bp = boff + 2 * bg;        // this lane's batch pair

        auto ldw = [&](int i, v2f& w1, v2f& d1, float4& w2, v2f& d2, v2f& w3, float& b3v) {
            const int n = (i << 4) + o1;
            w1  = *(const v2f*)(B1 + 2 * n);
            d1  = *(const v2f*)(c1 + 2 * n);
            w2  = *(const float4*)(B2 + 4 * n);
            d2  = *(const v2f*)(c2 + 2 * n);
            w3  = *(const v2f*)(B3 + 2 * n);
            b3v = c3[n];
        };

        v2f accA = zz, accB = zz;            // even/odd i -> 2 independent chains
        float bsum = 0.f;

        v2f w1, d1, d2, w3; float4 w2; float b3v;
        ldw(0, w1, d1, w2, d2, w3, b3v);

#pragma unroll 1
        for (int ii = 0; ii < 64; ++ii) {
            v2f nw1, nd1, nd2, nw3; float4 nw2; float nb3;
            ldw((ii + 1) & 63, nw1, nd1, nw2, nd2, nw3, nb3);

            const v2f W1X = {w1.x, w1.x}, W1Y = {w1.y, w1.y};
            const v2f D1X = {d1.x, d1.x}, D1Y = {d1.y, d1.y};
            const v2f W2X = {w2.x, w2.x}, W2Y = {w2.y, w2.y};
            const v2f W2Z = {w2.z, w2.z}, W2W = {w2.w, w2.w};
            const v2f D2X = {d2.x, d2.x}, D2Y = {d2.y, d2.y};
            const v2f W3X = {w3.x, w3.x}, W3Y = {w3.y, w3.y};

            const v2f hv = *(const v2f*)&ht[ii][bp];   // 4 distinct banks (bg*2)

            bsum += b3v;
            v2f m0 = __builtin_elementwise_fma(hv, W1X, D1X);
            v2f m1 = __builtin_elementwise_fma(hv, W1Y, D1Y);
            m0 = __builtin_elementwise_max(m0, zz);
            m1 = __builtin_elementwise_max(m1, zz);
            v2f t0 = __builtin_elementwise_fma(W2Y, m1, D2X);
            t0 = __builtin_elementwise_fma(W2X, m0, t0);
            v2f t1 = __builtin_elementwise_fma(W2W, m1, D2Y);
            t1 = __builtin_elementwise_fma(W2Z, m0, t1);
            t0 = __builtin_elementwise_max(t0, zz);
            t1 = __builtin_elementwise_max(t1, zz);
            if (ii & 1) {
                accB = __builtin_elementwise_fma(W3X, t0, accB);
                accB = __builtin_elementwise_fma(W3Y, t1, accB);
            } else {
                accA = __builtin_elementwise_fma(W3X, t0, accA);
                accA = __builtin_elementwise_fma(W3Y, t1, accA);
            }
            w1 = nw1; d1 = nd1; w2 = nw2; d2 = nd2; w3 = nw3; b3v = nb3;
        }

        const v2f r = accA + accB;
        out[(long)(bB0 + bp) * 16 + o1]     = r.x + bsum;
        out[(long)(bB0 + bp + 1) * 16 + o1] = r.y + bsum;
    }
}

extern "C" void kernel_launch(void* const* d_in, const int* in_sizes, int n_in,
                              void* d_out, int out_size, void* d_ws, size_t ws_size,
                              hipStream_t stream) {
    const float* x     = (const float*)d_in[0];
    const float* l0_W1 = (const float*)d_in[1];
    const float* l0_b1 = (const float*)d_in[2];
    const float* l0_W2 = (const float*)d_in[3];
    const float* l0_b2 = (const float*)d_in[4];
    const float* l0_W3 = (const float*)d_in[5];
    const float* l0_b3 = (const float*)d_in[6];
    const float* l1_W1 = (const float*)d_in[7];
    const float* l1_b1 = (const float*)d_in[8];
    const float* l1_W2 = (const float*)d_in[9];
    const float* l1_b2 = (const float*)d_in[10];
    const float* l1_W3 = (const float*)d_in[11];
    const float* l1_b3 = (const float*)d_in[12];

    float* outp = (float*)d_out;

    dim3 blk(512);
    dim3 grid(BATCH / TB);   // 256 blocks, 1 per CU
    hipLaunchKernelGGL(kan_fused, grid, blk, 0, stream,
                       x,
                       l0_W1, l0_b1, l0_W2, l0_b2, l0_W3, l0_b3,
                       l1_W1, l1_b1, l1_W2, l1_b2, l1_W3, l1_b3,
                       outp);
}

// Round 9
// 114.442 us; speedup vs baseline: 1.1510x; 1.1510x over previous
//
#include <hip/hip_runtime.h>

// Fused MLPKAN, round 9: LDS-resident weights.
// Evidence R2/R7/R8: kernel time ∝ weight-load instrs through L1/L2 (shared
// per-CU path saturates; TLP-insensitive). Fix: stage the 266 KB weight set
// into LDS once per block (global traffic = 266 KB/CU total), hot loop reads
// weights via ds_read (2-way / same-addr multicast = conflict-free).
// Grid 256 x 512 thr (8 waves, 2/SIMD), TB=64, 8 batches/wave end-to-end
// (no cross-wave partials). Weights chunked: 8 x (8 i) for layer 0,
// 2 x (32 i) for layer 1 -- every chunk = 512 subnets = identical 26 KB
// layout in one shared buffer; compute -> barrier -> stage -> barrier.
// Static LDS = 60 KB (xs 17.4 + ht 17.4 + wbuf 26).

typedef float v2f __attribute__((ext_vector_type(2)));

#define BATCH 16384
#define TB    64

// wbuf layout (float offsets) for one 512-subnet chunk
#define OW1 0
#define OB1 1024
#define OW2 2048
#define OB2 4096
#define OW3 5120
#define OB3 6144
#define WBUF_F 6656

__device__ __forceinline__ void copy16(float* __restrict__ dst,
                                       const float* __restrict__ src,
                                       int nbytes, int t) {
    // 16B per thread; array sizes (2/4/8 KB) keep participation wave-aligned
#pragma unroll 1
    for (int k = t * 16; k < nbytes; k += 512 * 16) {
        const float4 v = *(const float4*)((const char*)src + k);
        *(float4*)((char*)dst + k) = v;
    }
}

__device__ __forceinline__ void stage_chunk(float* wbuf,
    const float* W1, const float* b1, const float* W2,
    const float* b2, const float* W3, const float* b3,
    int s0, int t) {           // s0 = first subnet of the 512-subnet chunk
    copy16(wbuf + OW1, W1 + 2 * s0, 4096, t);
    copy16(wbuf + OB1, b1 + 2 * s0, 4096, t);
    copy16(wbuf + OW2, W2 + 4 * s0, 8192, t);
    copy16(wbuf + OB2, b2 + 2 * s0, 4096, t);
    copy16(wbuf + OW3, W3 + 2 * s0, 4096, t);
    copy16(wbuf + OB3, b3 + s0,     2048, t);
}

__global__ __launch_bounds__(512) void kan_fused(
    const float* __restrict__ x,
    const float* __restrict__ A1, const float* __restrict__ a1,
    const float* __restrict__ A2, const float* __restrict__ a2,
    const float* __restrict__ A3, const float* __restrict__ a3,
    const float* __restrict__ B1, const float* __restrict__ c1,
    const float* __restrict__ B2, const float* __restrict__ c2,
    const float* __restrict__ B3, const float* __restrict__ c3,
    float* __restrict__ out)
{
    __shared__ float xs[64][68];     // x transposed: xs[i][b]
    __shared__ float ht[64][68];     // h transposed: ht[i][b]
    __shared__ float wbuf[WBUF_F];   // current 512-subnet weight chunk

    const int t    = threadIdx.x;
    const int lane = t & 63;
    const int wave = t >> 6;          // 0..7
    const int boff = 8 * wave;        // this wave's 8 batches
    const int bB0  = blockIdx.x * TB;

    // ---- stage x transposed + first layer-0 weight chunk ----
#pragma unroll 1
    for (int k = t * 4; k < TB * 64; k += 512 * 4) {
        const float4 v = *(const float4*)(x + (long)bB0 * 64 + k);
        const int b = k >> 6, i = k & 63;
        xs[i][b] = v.x; xs[i + 1][b] = v.y; xs[i + 2][b] = v.z; xs[i + 3][b] = v.w;
    }
    stage_chunk(wbuf, A1, a1, A2, a2, A3, a3, 0, t);
    __syncthreads();

    const v2f zz = {0.f, 0.f};

    // ================= layer 0: 64 -> 64, 8 chunks of 8 i =================
    const int o = lane;
    v2f acc[4] = {zz, zz, zz, zz};
    float bsum = 0.f;

#pragma unroll 1
    for (int c = 0; c < 8; ++c) {
#pragma unroll 2
        for (int ic = 0; ic < 8; ++ic) {
            const int i = 8 * c + ic;
            const int n = (ic << 6) + o;                       // chunk-local subnet
            const v2f    w1 = *(const v2f*)(wbuf + OW1 + 2 * n);   // 2-way: free
            const v2f    d1 = *(const v2f*)(wbuf + OB1 + 2 * n);
            const float4 w2 = *(const float4*)(wbuf + OW2 + 4 * n);
            const v2f    d2 = *(const v2f*)(wbuf + OB2 + 2 * n);
            const v2f    w3 = *(const v2f*)(wbuf + OW3 + 2 * n);
            bsum += wbuf[OB3 + n];

            const v2f W1X = {w1.x, w1.x}, W1Y = {w1.y, w1.y};
            const v2f D1X = {d1.x, d1.x}, D1Y = {d1.y, d1.y};
            const v2f W2X = {w2.x, w2.x}, W2Y = {w2.y, w2.y};
            const v2f W2Z = {w2.z, w2.z}, W2W = {w2.w, w2.w};
            const v2f D2X = {d2.x, d2.x}, D2Y = {d2.y, d2.y};
            const v2f W3X = {w3.x, w3.x}, W3Y = {w3.y, w3.y};

            const float4 xv0 = *(const float4*)&xs[i][boff];   // broadcast: free
            const float4 xv1 = *(const float4*)&xs[i][boff + 4];
            const float4 xq[2] = {xv0, xv1};
            const v2f* xp = (const v2f*)xq;

#pragma unroll
            for (int jp = 0; jp < 4; ++jp) {                   // 2 batches/iter
                v2f m0 = __builtin_elementwise_fma(xp[jp], W1X, D1X);
                v2f m1 = __builtin_elementwise_fma(xp[jp], W1Y, D1Y);
                m0 = __builtin_elementwise_max(m0, zz);
                m1 = __builtin_elementwise_max(m1, zz);
                v2f t0 = __builtin_elementwise_fma(W2Y, m1, D2X);
                t0 = __builtin_elementwise_fma(W2X, m0, t0);
                v2f t1 = __builtin_elementwise_fma(W2W, m1, D2Y);
                t1 = __builtin_elementwise_fma(W2Z, m0, t1);
                t0 = __builtin_elementwise_max(t0, zz);
                t1 = __builtin_elementwise_max(t1, zz);
                acc[jp] = __builtin_elementwise_fma(W3X, t0, acc[jp]);
                acc[jp] = __builtin_elementwise_fma(W3Y, t1, acc[jp]);
            }
        }
        __syncthreads();                                       // all done with wbuf
        if (c < 7) stage_chunk(wbuf, A1, a1, A2, a2, A3, a3, 512 * (c + 1), t);
        else       stage_chunk(wbuf, B1, c1, B2, c2, B3, c3, 0, t);  // layer1 chunk 0
        __syncthreads();                                       // staged data visible
    }

    // write this wave's 8 batches, transposed for layer 1
#pragma unroll
    for (int jp = 0; jp < 4; ++jp) {
        ht[o][boff + 2 * jp]     = acc[jp].x + bsum;
        ht[o][boff + 2 * jp + 1] = acc[jp].y + bsum;
    }
    __syncthreads();

    // ================= layer 1: 64 -> 16, 2 chunks of 32 i =================
    const int o1 = lane & 15;
    const int bg = lane >> 4;
    const int bp = boff + 2 * bg;          // this lane's batch pair
    v2f accA = zz, accB = zz;
    float bsum1 = 0.f;

#pragma unroll 1
    for (int cc = 0; cc < 2; ++cc) {
#pragma unroll 4
        for (int ii = 0; ii < 32; ++ii) {
            const int i = 32 * cc + ii;
            const int n = (ii << 4) + o1;                      // chunk-local subnet
            const v2f    w1 = *(const v2f*)(wbuf + OW1 + 2 * n);   // 4-way same-addr: free
            const v2f    d1 = *(const v2f*)(wbuf + OB1 + 2 * n);
            const float4 w2 = *(const float4*)(wbuf + OW2 + 4 * n);
            const v2f    d2 = *(const v2f*)(wbuf + OB2 + 2 * n);
            const v2f    w3 = *(const v2f*)(wbuf + OW3 + 2 * n);
            bsum1 += wbuf[OB3 + n];

            const v2f W1X = {w1.x, w1.x}, W1Y = {w1.y, w1.y};
            const v2f D1X = {d1.x, d1.x}, D1Y = {d1.y, d1.y};
            const v2f W2X = {w2.x, w2.x}, W2Y = {w2.y, w2.y};
            const v2f W2Z = {w2.z, w2.z}, W2W = {w2.w, w2.w};
            const v2f D2X = {d2.x, d2.x}, D2Y = {d2.y, d2.y};
            const v2f W3X = {w3.x, w3.x}, W3Y = {w3.y, w3.y};

            const v2f hv = *(const v2f*)&ht[i][bp];

            v2f m0 = __builtin_elementwise_fma(hv, W1X, D1X);
            v2f m1 = __builtin_elementwise_fma(hv, W1Y, D1Y);
            m0 = __builtin_elementwise_max(m0, zz);
            m1 = __builtin_elementwise_max(m1, zz);
            v2f t0 = __builtin_elementwise_fma(W2Y, m1, D2X);
            t0 = __builtin_elementwise_fma(W2X, m0, t0);
            v2f t1 = __builtin_elementwise_fma(W2W, m1, D2Y);
            t1 = __builtin_elementwise_fma(W2Z, m0, t1);
            t0 = __builtin_elementwise_max(t0, zz);
            t1 = __builtin_elementwise_max(t1, zz);
            if (ii & 1) {
                accB = __builtin_elementwise_fma(W3X, t0, accB);
                accB = __builtin_elementwise_fma(W3Y, t1, accB);
            } else {
                accA = __builtin_elementwise_fma(W3X, t0, accA);
                accA = __builtin_elementwise_fma(W3Y, t1, accA);
            }
        }
        __syncthreads();
        if (cc == 0) {
            stage_chunk(wbuf, B1, c1, B2, c2, B3, c3, 512, t);  // layer1 chunk 1
            __syncthreads();
        }
    }

    const v2f r = accA + accB;
    out[(long)(bB0 + bp) * 16 + o1]     = r.x + bsum1;
    out[(long)(bB0 + bp + 1) * 16 + o1] = r.y + bsum1;
}

extern "C" void kernel_launch(void* const* d_in, const int* in_sizes, int n_in,
                              void* d_out, int out_size, void* d_ws, size_t ws_size,
                              hipStream_t stream) {
    const float* x     = (const float*)d_in[0];
    const float* l0_W1 = (const float*)d_in[1];
    const float* l0_b1 = (const float*)d_in[2];
    const float* l0_W2 = (const float*)d_in[3];
    const float* l0_b2 = (const float*)d_in[4];
    const float* l0_W3 = (const float*)d_in[5];
    const float* l0_b3 = (const float*)d_in[6];
    const float* l1_W1 = (const float*)d_in[7];
    const float* l1_b1 = (const float*)d_in[8];
    const float* l1_W2 = (const float*)d_in[9];
    const float* l1_b2 = (const float*)d_in[10];
    const float* l1_W3 = (const float*)d_in[11];
    const float* l1_b3 = (const float*)d_in[12];

    float* outp = (float*)d_out;

    dim3 blk(512);
    dim3 grid(BATCH / TB);   // 256 blocks, 1 per CU
    hipLaunchKernelGGL(kan_fused, grid, blk, 0, stream,
                       x,
                       l0_W1, l0_b1, l0_W2, l0_b2, l0_W3, l0_b3,
                       l1_W1, l1_b1, l1_W2, l1_b2, l1_W3, l1_b3,
                       outp);
}

// Round 10
// 114.261 us; speedup vs baseline: 1.1529x; 1.0016x over previous
//
#include <hip/hip_runtime.h>

// Fused MLPKAN, round 10: LDS weights + i-partitioned waves + lane-tiled L1.
// Grid 256 x 512 thr (8 waves), TB=64. LDS pipe is the bottleneck (R9 model:
// ~64k cyc/CU, dominated by redundant weight re-reads). Changes:
//  - L0: wave = (ih, bq): 32 i x 16 b. Weight reads halved. Partials in two
//    planes hpA/hpB; hpB OVERLAYS xs (dead after L0).
//  - L1: lane = (ig, o1): one ds_read serves 64 distinct subnets (4 i x 16 o).
//    ig reduced via shfl_xor; ih merged via op planes overlaid on wbuf.
//  - Weights staged in 10 chunks of 512 subnets (26 KB) through one buffer;
//    chunk spans stay contiguous because the i-partition is chunk-local.
// LDS total 60 KB: xs/hpB 17.4 + hpA 17.4 + wbuf 26.

typedef float v2f __attribute__((ext_vector_type(2)));

#define BATCH 16384
#define TB    64

// wbuf layout (float offsets) for one 512-subnet chunk
#define OW1 0
#define OB1 1024
#define OW2 2048
#define OB2 4096
#define OW3 5120
#define OB3 6144
#define WBUF_F 6656

__device__ __forceinline__ void copy16(float* __restrict__ dst,
                                       const float* __restrict__ src,
                                       int nbytes, int t) {
#pragma unroll 1
    for (int k = t * 16; k < nbytes; k += 512 * 16) {
        const float4 v = *(const float4*)((const char*)src + k);
        *(float4*)((char*)dst + k) = v;
    }
}

__device__ __forceinline__ void stage_chunk(float* wbuf,
    const float* W1, const float* b1, const float* W2,
    const float* b2, const float* W3, const float* b3,
    int s0, int t) {
    copy16(wbuf + OW1, W1 + 2 * s0, 4096, t);
    copy16(wbuf + OB1, b1 + 2 * s0, 4096, t);
    copy16(wbuf + OW2, W2 + 4 * s0, 8192, t);
    copy16(wbuf + OB2, b2 + 2 * s0, 4096, t);
    copy16(wbuf + OW3, W3 + 2 * s0, 4096, t);
    copy16(wbuf + OB3, b3 + s0,     2048, t);
}

__global__ __launch_bounds__(512, 2) void kan_fused(
    const float* __restrict__ x,
    const float* __restrict__ A1, const float* __restrict__ a1,
    const float* __restrict__ A2, const float* __restrict__ a2,
    const float* __restrict__ A3, const float* __restrict__ a3,
    const float* __restrict__ B1, const float* __restrict__ c1,
    const float* __restrict__ B2, const float* __restrict__ c2,
    const float* __restrict__ B3, const float* __restrict__ c3,
    float* __restrict__ out)
{
    __shared__ float xsb[64][68];    // xs during L0, hpB afterwards (overlay)
    __shared__ float hpA[64][68];    // L0 partial plane, ih=0
    __shared__ float wbuf[WBUF_F];   // weight chunk; op planes at the end

    float (*xs)[68]  = xsb;
    float (*hpB)[68] = xsb;

    const int t    = threadIdx.x;
    const int lane = t & 63;
    const int wave = t >> 6;          // 0..7
    const int ih   = wave & 1;        // i-half (interleaved, chunk-local)
    const int bq   = wave >> 1;       // batch quarter
    const int boff = 16 * bq;         // this wave's 16 batches
    const int bB0  = blockIdx.x * TB;

    // ---- stage x transposed + first layer-0 chunk ----
#pragma unroll 1
    for (int k = t * 4; k < TB * 64; k += 512 * 4) {
        const float4 v = *(const float4*)(x + (long)bB0 * 64 + k);
        const int b = k >> 6, i = k & 63;
        xs[i][b] = v.x; xs[i + 1][b] = v.y; xs[i + 2][b] = v.z; xs[i + 3][b] = v.w;
    }
    stage_chunk(wbuf, A1, a1, A2, a2, A3, a3, 0, t);
    __syncthreads();

    const v2f zz = {0.f, 0.f};

    // ================= layer 0: 8 chunks x (4 i per wave) =================
    const int o = lane;
    v2f acc[8];
#pragma unroll
    for (int j = 0; j < 8; ++j) acc[j] = zz;
    float bsum = 0.f;

#pragma unroll 1
    for (int p = 0; p < 8; ++p) {
#pragma unroll 2
        for (int ii = 0; ii < 4; ++ii) {
            const int li = 4 * ih + ii;          // chunk-local i
            const int gi = 8 * p + li;           // global i (xs row)
            const int n  = (li << 6) + o;
            const v2f    w1 = *(const v2f*)(wbuf + OW1 + 2 * n);
            const v2f    d1 = *(const v2f*)(wbuf + OB1 + 2 * n);
            const float4 w2 = *(const float4*)(wbuf + OW2 + 4 * n);
            const v2f    d2 = *(const v2f*)(wbuf + OB2 + 2 * n);
            const v2f    w3 = *(const v2f*)(wbuf + OW3 + 2 * n);
            bsum += wbuf[OB3 + n];

            const v2f W1X = {w1.x, w1.x}, W1Y = {w1.y, w1.y};
            const v2f D1X = {d1.x, d1.x}, D1Y = {d1.y, d1.y};
            const v2f W2X = {w2.x, w2.x}, W2Y = {w2.y, w2.y};
            const v2f W2Z = {w2.z, w2.z}, W2W = {w2.w, w2.w};
            const v2f D2X = {d2.x, d2.x}, D2Y = {d2.y, d2.y};
            const v2f W3X = {w3.x, w3.x}, W3Y = {w3.y, w3.y};

            const float4 xv0 = *(const float4*)&xs[gi][boff];      // broadcast
            const float4 xv1 = *(const float4*)&xs[gi][boff + 4];
            const float4 xv2 = *(const float4*)&xs[gi][boff + 8];
            const float4 xv3 = *(const float4*)&xs[gi][boff + 12];
            const float4 xq[4] = {xv0, xv1, xv2, xv3};
            const v2f* xp = (const v2f*)xq;

#pragma unroll
            for (int jp = 0; jp < 8; ++jp) {                       // 2 batches/iter
                v2f m0 = __builtin_elementwise_fma(xp[jp], W1X, D1X);
                v2f m1 = __builtin_elementwise_fma(xp[jp], W1Y, D1Y);
                m0 = __builtin_elementwise_max(m0, zz);
                m1 = __builtin_elementwise_max(m1, zz);
                v2f t0 = __builtin_elementwise_fma(W2Y, m1, D2X);
                t0 = __builtin_elementwise_fma(W2X, m0, t0);
                v2f t1 = __builtin_elementwise_fma(W2W, m1, D2Y);
                t1 = __builtin_elementwise_fma(W2Z, m0, t1);
                t0 = __builtin_elementwise_max(t0, zz);
                t1 = __builtin_elementwise_max(t1, zz);
                acc[jp] = __builtin_elementwise_fma(W3X, t0, acc[jp]);
                acc[jp] = __builtin_elementwise_fma(W3Y, t1, acc[jp]);
            }
        }
        __syncthreads();                                           // wbuf done
        if (p < 7) stage_chunk(wbuf, A1, a1, A2, a2, A3, a3, 512 * (p + 1), t);
        else       stage_chunk(wbuf, B1, c1, B2, c2, B3, c3, 0, t);
        __syncthreads();
    }

    // ---- write partial planes (xs is dead -> hpB may overlay it) ----
    {
        float (*hp)[68] = ih ? hpB : hpA;
#pragma unroll
        for (int jp = 0; jp < 8; ++jp) {
            hp[o][boff + 2 * jp]     = acc[jp].x + bsum;
            hp[o][boff + 2 * jp + 1] = acc[jp].y + bsum;
        }
    }
    __syncthreads();

    // ================= layer 1: 2 chunks x (4 steps x 4 i-per-read) =========
    const int o1 = lane & 15;
    const int ig = lane >> 4;            // i-offset within a 4-i step
    v2f acc1[8];
#pragma unroll
    for (int j = 0; j < 8; ++j) acc1[j] = zz;
    float bsum1 = 0.f;

#pragma unroll 1
    for (int q = 0; q < 2; ++q) {
#pragma unroll 2
        for (int s = 0; s < 4; ++s) {
            const int li = 16 * ih + 4 * s + ig;   // chunk-local i (this lane's)
            const int gi = 32 * q + li;            // global i
            const int n  = (li << 4) + o1;         // 64 consecutive n per wave
            const v2f    w1 = *(const v2f*)(wbuf + OW1 + 2 * n);
            const v2f    d1 = *(const v2f*)(wbuf + OB1 + 2 * n);
            const float4 w2 = *(const float4*)(wbuf + OW2 + 4 * n);
            const v2f    d2 = *(const v2f*)(wbuf + OB2 + 2 * n);
            const v2f    w3 = *(const v2f*)(wbuf + OW3 + 2 * n);
            bsum1 += wbuf[OB3 + n];

            const v2f W1X = {w1.x, w1.x}, W1Y = {w1.y, w1.y};
            const v2f D1X = {d1.x, d1.x}, D1Y = {d1.y, d1.y};
            const v2f W2X = {w2.x, w2.x}, W2Y = {w2.y, w2.y};
            const v2f W2Z = {w2.z, w2.z}, W2W = {w2.w, w2.w};
            const v2f D2X = {d2.x, d2.x}, D2Y = {d2.y, d2.y};
            const v2f W3X = {w3.x, w3.x}, W3Y = {w3.y, w3.y};

            // h = hpA + hpB for this lane's i, 16 batches
            v2f hv[8];
#pragma unroll
            for (int m = 0; m < 4; ++m) {
                const float4 av = *(const float4*)&hpA[gi][boff + 4 * m];
                const float4 bv = *(const float4*)&hpB[gi][boff + 4 * m];
                hv[2 * m]     = v2f{av.x + bv.x, av.y + bv.y};
                hv[2 * m + 1] = v2f{av.z + bv.z, av.w + bv.w};
            }

#pragma unroll
            for (int jp = 0; jp < 8; ++jp) {
                v2f m0 = __builtin_elementwise_fma(hv[jp], W1X, D1X);
                v2f m1 = __builtin_elementwise_fma(hv[jp], W1Y, D1Y);
                m0 = __builtin_elementwise_max(m0, zz);
                m1 = __builtin_elementwise_max(m1, zz);
                v2f t0 = __builtin_elementwise_fma(W2Y, m1, D2X);
                t0 = __builtin_elementwise_fma(W2X, m0, t0);
                v2f t1 = __builtin_elementwise_fma(W2W, m1, D2Y);
                t1 = __builtin_elementwise_fma(W2Z, m0, t1);
                t0 = __builtin_elementwise_max(t0, zz);
                t1 = __builtin_elementwise_max(t1, zz);
                acc1[jp] = __builtin_elementwise_fma(W3X, t0, acc1[jp]);
                acc1[jp] = __builtin_elementwise_fma(W3Y, t1, acc1[jp]);
            }
        }
        __syncthreads();                                           // wbuf done
        if (q == 0) {
            stage_chunk(wbuf, B1, c1, B2, c2, B3, c3, 512, t);
            __syncthreads();
        }
    }

    // ---- reduce over ig (lanes 16 apart) ----
#pragma unroll
    for (int jp = 0; jp < 8; ++jp) {
        float vx = acc1[jp].x, vy = acc1[jp].y;
        vx += __shfl_xor(vx, 16, 64); vx += __shfl_xor(vx, 32, 64);
        vy += __shfl_xor(vy, 16, 64); vy += __shfl_xor(vy, 32, 64);
        acc1[jp].x = vx; acc1[jp].y = vy;
    }
    bsum1 += __shfl_xor(bsum1, 16, 64);
    bsum1 += __shfl_xor(bsum1, 32, 64);

    // ---- op planes overlay wbuf (dead after last q barrier) ----
    float* opA = wbuf;          // [64][16]
    float* opB = wbuf + 1024;
    if (ig == 0) {
        float* op = ih ? opB : opA;
#pragma unroll
        for (int jp = 0; jp < 8; ++jp) {
            op[(boff + 2 * jp) * 16 + o1]     = acc1[jp].x + bsum1;
            op[(boff + 2 * jp + 1) * 16 + o1] = acc1[jp].y + bsum1;
        }
    }
    __syncthreads();

    // ---- store: out = opA + opB, 1024 floats, float4 coalesced ----
    if (t < 256) {
        const int f = t * 4;
        const float4 u = *(const float4*)(opA + f);
        const float4 v = *(const float4*)(opB + f);
        float4 r;
        r.x = u.x + v.x; r.y = u.y + v.y; r.z = u.z + v.z; r.w = u.w + v.w;
        *(float4*)(out + (long)bB0 * 16 + f) = r;
    }
}

extern "C" void kernel_launch(void* const* d_in, const int* in_sizes, int n_in,
                              void* d_out, int out_size, void* d_ws, size_t ws_size,
                              hipStream_t stream) {
    const float* x     = (const float*)d_in[0];
    const float* l0_W1 = (const float*)d_in[1];
    const float* l0_b1 = (const float*)d_in[2];
    const float* l0_W2 = (const float*)d_in[3];
    const float* l0_b2 = (const float*)d_in[4];
    const float* l0_W3 = (const float*)d_in[5];
    const float* l0_b3 = (const float*)d_in[6];
    const float* l1_W1 = (const float*)d_in[7];
    const float* l1_b1 = (const float*)d_in[8];
    const float* l1_W2 = (const float*)d_in[9];
    const float* l1_b2 = (const float*)d_in[10];
    const float* l1_W3 = (const float*)d_in[11];
    const float* l1_b3 = (const float*)d_in[12];

    float* outp = (float*)d_out;

    dim3 blk(512);
    dim3 grid(BATCH / TB);   // 256 blocks, 1 per CU
    hipLaunchKernelGGL(kan_fused, grid, blk, 0, stream,
                       x,
                       l0_W1, l0_b1, l0_W2, l0_b2, l0_W3, l0_b3,
                       l1_W1, l1_b1, l1_W2, l1_b2, l1_W3, l1_b3,
                       outp);
}

// Round 11
// 104.545 us; speedup vs baseline: 1.2600x; 1.0929x over previous
//
#include <hip/hip_runtime.h>

// Fused MLPKAN, round 11: packed-f16 datapath + fully LDS-resident weights.
//  - Pre-kernel converts weights to packed f16: per subnet 6 u32
//    {w1pk, b1pk, w2col0pk, w2col1pk, b2pk, w3pk} split into a uint4 array
//    (b128 read) + uint2 array (b64 read). Also precomputes sum_i b3 per
//    output column (bsum0[64], bsum1[16]) -> b3 leaves the hot loop.
//  - Inner eval = 6 VALU/batch-subnet: v_pk_fma_f16, v_pk_max_f16,
//    2x v_pk_fma_f16 (half-broadcast), v_pk_max_f16, v_dot2_f32_f16
//    (f32 accumulator -> i-sum stays fp32-accurate).
//  - All 5120 subnets' weights live in dynamic LDS (120 KB) the whole
//    kernel + x/h as dup-f16 u32 (17 KB) = 140288 B (hipFuncSetAttribute).
//    NO chunk staging, 2 barriers total.
//  - Waves partition batches only (8 b/wave end-to-end): no cross-wave
//    partials, h written/read only in the wave's own columns, L1 results
//    shfl-reduced over ig and stored straight to global.
// Grid 256 x 512 thr (8 waves, 2/SIMD), TB=64 batches/block.

typedef unsigned int u32;
typedef _Float16 h2 __attribute__((ext_vector_type(2)));

#define BATCH 16384
#define NW    5120                     // 4096 L0 + 1024 L1 subnets
#define SMEM_U32 (6 * NW + 64 * 68)    // weights + xd  = 35072 u32
#define SMEM_BYTES (SMEM_U32 * 4)      // 140288 B

#if defined(__has_builtin)
#if __has_builtin(__builtin_amdgcn_fdot2)
#define FDOT2(a, b, c) __builtin_amdgcn_fdot2((a), (b), (c), false)
#endif
#endif
#ifndef FDOT2
#define FDOT2(a, b, c) ((c) + (float)(a).x * (float)(b).x + (float)(a).y * (float)(b).y)
#endif

static __device__ __forceinline__ u32 pack2f(float a, float b) {
    h2 v = {(_Float16)a, (_Float16)b};
    return __builtin_bit_cast(u32, v);
}
static __device__ __forceinline__ u32 dupf(float a) {
    _Float16 h = (_Float16)a;
    h2 v = {h, h};
    return __builtin_bit_cast(u32, v);
}
static __device__ __forceinline__ h2 bch(u32 u) { return __builtin_bit_cast(h2, u); }

// 8 batches x 1 subnet: 6 VALU per batch
static __device__ __forceinline__ void eval8(const u32* xq, uint4 A, uint2 B, float* acc) {
    const h2 w1 = bch(A.x), b1 = bch(A.y), c0 = bch(A.z), c1 = bch(A.w);
    const h2 b2 = bch(B.x), w3 = bch(B.y);
    const h2 z = {(_Float16)0.f, (_Float16)0.f};
#pragma unroll
    for (int j = 0; j < 8; ++j) {
        h2 xd = bch(xq[j]);
        h2 m = __builtin_elementwise_fma(xd, w1, b1);          // v_pk_fma_f16
        m = __builtin_elementwise_max(m, z);                   // v_pk_max_f16
        h2 mlo = __builtin_shufflevector(m, m, 0, 0);          // op_sel candidates
        h2 mhi = __builtin_shufflevector(m, m, 1, 1);
        h2 tt = __builtin_elementwise_fma(mlo, c0, b2);
        tt = __builtin_elementwise_fma(mhi, c1, tt);
        tt = __builtin_elementwise_max(tt, z);
        acc[j] = FDOT2(w3, tt, acc[j]);                        // v_dot2_f32_f16
    }
}

// ---------------- weight conversion pre-kernel ----------------
__global__ __launch_bounds__(256) void kan_convert(
    const float* __restrict__ A1, const float* __restrict__ a1,
    const float* __restrict__ A2, const float* __restrict__ a2,
    const float* __restrict__ A3, const float* __restrict__ a3,
    const float* __restrict__ B1, const float* __restrict__ c1,
    const float* __restrict__ B2, const float* __restrict__ c2,
    const float* __restrict__ B3, const float* __restrict__ c3,
    u32* __restrict__ ws)
{
    const int blk = blockIdx.x;
    if (blk < 20) {
        const int n = blk * 256 + threadIdx.x;     // 0..5119
        const float *W1, *B1p, *W2, *B2p, *W3;
        int s;
        if (n < 4096) { s = n;        W1 = A1; B1p = a1; W2 = A2; B2p = a2; W3 = A3; }
        else          { s = n - 4096; W1 = B1; B1p = c1; W2 = B2; B2p = c2; W3 = B3; }
        const float w1x = W1[2 * s], w1y = W1[2 * s + 1];
        const float b1x = B1p[2 * s], b1y = B1p[2 * s + 1];
        const float4 w2 = *(const float4*)(W2 + 4 * s);   // [k0h0,k0h1,k1h0,k1h1]
        const float b2x = B2p[2 * s], b2y = B2p[2 * s + 1];
        const float w3x = W3[2 * s], w3y = W3[2 * s + 1];
        uint4 A;
        A.x = pack2f(w1x, w1y);
        A.y = pack2f(b1x, b1y);
        A.z = pack2f(w2.x, w2.z);    // col0: *m0
        A.w = pack2f(w2.y, w2.w);    // col1: *m1
        *(uint4*)(ws + 4 * n) = A;
        uint2 Bv;
        Bv.x = pack2f(b2x, b2y);
        Bv.y = pack2f(w3x, w3y);
        *(uint2*)(ws + 4 * NW + 2 * n) = Bv;
    } else {
        const int t = threadIdx.x;
        float* bs = (float*)(ws + 6 * NW);
        if (t < 64) {
            float s = 0.f;
            for (int i = 0; i < 64; ++i) s += a3[i * 64 + t];
            bs[t] = s;
        } else if (t < 80) {
            const int o = t - 64;
            float s = 0.f;
            for (int i = 0; i < 64; ++i) s += c3[i * 16 + o];
            bs[64 + o] = s;
        }
    }
}

// ---------------- main fused kernel ----------------
__global__ __launch_bounds__(512) void kan_main(
    const float* __restrict__ x, const u32* __restrict__ ws, float* __restrict__ out)
{
    extern __shared__ u32 smem[];
    u32* wA = smem;                 // [4*NW] uint4/subnet
    u32* wB = smem + 4 * NW;        // [2*NW] uint2/subnet
    u32* xd = smem + 6 * NW;        // [64][68] dup-f16 x, then dup-f16 h

    const int t    = threadIdx.x;
    const int lane = t & 63;
    const int wave = t >> 6;        // 0..7 = batch-octant
    const int boff = 8 * wave;      // this wave's 8 batches
    const int bB0  = blockIdx.x * 64;

    // stage all weights (linear 120 KB copy) ...
#pragma unroll
    for (int k = t * 4; k < 6 * NW; k += 512 * 4) {
        const uint4 v = *(const uint4*)(ws + k);
        *(uint4*)(smem + k) = v;
    }
    // ... and x, converted to dup-f16, transposed
#pragma unroll
    for (int k = t * 4; k < 64 * 64; k += 512 * 4) {
        const float4 v = *(const float4*)(x + (long)bB0 * 64 + k);
        const int b = k >> 6, i = k & 63;
        xd[(i    ) * 68 + b] = dupf(v.x);
        xd[(i + 1) * 68 + b] = dupf(v.y);
        xd[(i + 2) * 68 + b] = dupf(v.z);
        xd[(i + 3) * 68 + b] = dupf(v.w);
    }
    __syncthreads();

    // ========== layer 0: lane = o, wave sweeps all 64 i for its 8 batches ====
    float acc[8];
#pragma unroll
    for (int j = 0; j < 8; ++j) acc[j] = 0.f;

    {
        auto ldw = [&](int i, uint4& A, uint2& B) {
            const int n = (i << 6) + lane;
            A = *(const uint4*)(wA + 4 * n);       // ds_read_b128, coalesced
            B = *(const uint2*)(wB + 2 * n);       // ds_read_b64, 2-way free
        };
        auto ldx = [&](int i, uint4* q) {
            const uint4* p = (const uint4*)(xd + i * 68 + boff);  // broadcast
            q[0] = p[0]; q[1] = p[1];
        };
        uint4 A; uint2 B; uint4 xq[2];
        ldw(0, A, B); ldx(0, xq);
#pragma unroll 2
        for (int ii = 0; ii < 64; ++ii) {
            uint4 nA; uint2 nB; uint4 nx[2];
            const int nxt = (ii + 1) & 63;
            ldw(nxt, nA, nB);                      // 1-deep pipeline
            ldx(nxt, nx);
            eval8((const u32*)xq, A, B, acc);
            A = nA; B = nB; xq[0] = nx[0]; xq[1] = nx[1];
        }
    }
    const float bs0 = ((const float*)(ws + 6 * NW))[lane];
    // h write: row = this lane's o, cols = this wave's own 8 batches (disjoint)
#pragma unroll
    for (int j = 0; j < 8; ++j)
        xd[lane * 68 + boff + j] = dupf(acc[j] + bs0);
    __syncthreads();

    // ========== layer 1: lane = (ig, o1); 16 steps of 4 i; 8 batches ==========
    const int o1 = lane & 15;
    const int ig = lane >> 4;
    float ac1[8];
#pragma unroll
    for (int j = 0; j < 8; ++j) ac1[j] = 0.f;

    {
        auto ldw = [&](int s, uint4& A, uint2& B) {
            const int n = 4096 + ((4 * s + ig) << 4) + o1;   // 64 consecutive/wave
            A = *(const uint4*)(wA + 4 * n);
            B = *(const uint2*)(wB + 2 * n);
        };
        auto ldh = [&](int s, uint4* q) {
            const uint4* p = (const uint4*)(xd + (4 * s + ig) * 68 + boff);
            q[0] = p[0]; q[1] = p[1];
        };
        uint4 A; uint2 B; uint4 hq[2];
        ldw(0, A, B); ldh(0, hq);
#pragma unroll 2
        for (int s = 0; s < 16; ++s) {
            uint4 nA; uint2 nB; uint4 nh[2];
            const int nxt = (s + 1) & 15;
            ldw(nxt, nA, nB);
            ldh(nxt, nh);
            eval8((const u32*)hq, A, B, ac1);
            A = nA; B = nB; hq[0] = nh[0]; hq[1] = nh[1];
        }
    }

    // reduce over ig (lane bits 4,5), add bsum1, store direct to global
    const float bs1 = ((const float*)(ws + 6 * NW))[64 + o1];
#pragma unroll
    for (int j = 0; j < 8; ++j) {
        float v = ac1[j];
        v += __shfl_xor(v, 16, 64);
        v += __shfl_xor(v, 32, 64);
        if (ig == 0)
            out[(long)(bB0 + boff + j) * 16 + o1] = v + bs1;
    }
}

extern "C" void kernel_launch(void* const* d_in, const int* in_sizes, int n_in,
                              void* d_out, int out_size, void* d_ws, size_t ws_size,
                              hipStream_t stream) {
    const float* x     = (const float*)d_in[0];
    const float* l0_W1 = (const float*)d_in[1];
    const float* l0_b1 = (const float*)d_in[2];
    const float* l0_W2 = (const float*)d_in[3];
    const float* l0_b2 = (const float*)d_in[4];
    const float* l0_W3 = (const float*)d_in[5];
    const float* l0_b3 = (const float*)d_in[6];
    const float* l1_W1 = (const float*)d_in[7];
    const float* l1_b1 = (const float*)d_in[8];
    const float* l1_W2 = (const float*)d_in[9];
    const float* l1_b2 = (const float*)d_in[10];
    const float* l1_W3 = (const float*)d_in[11];
    const float* l1_b3 = (const float*)d_in[12];

    u32*   ws   = (u32*)d_ws;
    float* outp = (float*)d_out;

    static int attr_done = -1;  // idempotent; same call every launch
    (void)attr_done;
    hipFuncSetAttribute((const void*)kan_main,
                        hipFuncAttributeMaxDynamicSharedMemorySize, SMEM_BYTES);

    hipLaunchKernelGGL(kan_convert, dim3(21), dim3(256), 0, stream,
                       l0_W1, l0_b1, l0_W2, l0_b2, l0_W3, l0_b3,
                       l1_W1, l1_b1, l1_W2, l1_b2, l1_W3, l1_b3, ws);

    hipLaunchKernelGGL(kan_main, dim3(BATCH / 64), dim3(512), SMEM_BYTES, stream,
                       x, ws, outp);
}